// Round 6
// baseline (192.257 us; speedup 1.0000x reference)
//
#include <hip/hip_runtime.h>
#include <hip/hip_bf16.h>
#include <cstdint>

#define T_TOK 2048
#define HID   2048
#define NEXP  64
#define TOPK  6
#define NLOC  8
#define ITR   1408
#define ITR2  2816
#define NSLOT (T_TOK * TOPK)
#define NK1   32   // HID/64
#define NK2   22   // ITR/64

// workspace layout (bytes)
#define OFF_CNT   0
#define OFF_CNT2  32
#define OFF_OFFS  64
#define OFF_TOPID 4096
#define OFF_TOPW  (OFF_TOPID + T_TOK * TOPK * 4)
#define OFF_TOK   (OFF_TOPW  + T_TOK * TOPK * 4)
#define OFF_WOF   (OFF_TOK   + NSLOT * 4)
#define OFF_XBF   (OFF_WOF   + NSLOT * 4)
#define OFF_ABUF  (OFF_XBF   + (size_t)T_TOK * HID * 2)

typedef __attribute__((ext_vector_type(4))) float f32x4;
typedef __attribute__((ext_vector_type(8))) short s16x8;
typedef __attribute__((ext_vector_type(4))) short s16x4;

__device__ __forceinline__ short f2bf(float f) {
    union { float f; unsigned u; } v; v.f = f;
    unsigned r = v.u + 0x7FFFu + ((v.u >> 16) & 1u);
    return (short)(r >> 16);
}

// raw barrier: LDS visibility via lgkmcnt(0), but vmem prefetch stays in flight
#define BAR() do {                                            \
    asm volatile("s_waitcnt lgkmcnt(0)" ::: "memory");        \
    __builtin_amdgcn_s_barrier();                             \
    asm volatile("" ::: "memory");                            \
} while (0)

// ---------------- prep: zero d_out + counters, cvt x -> bf16 ----------------
__global__ __launch_bounds__(256) void k_prep(const float* __restrict__ x,
                                              short* __restrict__ xbf,
                                              float* __restrict__ out,
                                              int* __restrict__ cnt)
{
    const int r = blockIdx.x;            // 2048 rows
    const int c = threadIdx.x * 8;
    const float4 a = *(const float4*)&x[(size_t)r * HID + c];
    const float4 b = *(const float4*)&x[(size_t)r * HID + c + 4];
    s16x8 v = { f2bf(a.x), f2bf(a.y), f2bf(a.z), f2bf(a.w),
                f2bf(b.x), f2bf(b.y), f2bf(b.z), f2bf(b.w) };
    *(s16x8*)&xbf[(size_t)r * HID + c] = v;
    float4 z = {0.f, 0.f, 0.f, 0.f};
    *(float4*)&out[(size_t)r * HID + c] = z;
    *(float4*)&out[(size_t)r * HID + c + 4] = z;
    if (r == 0 && threadIdx.x < 16) cnt[threadIdx.x] = 0;
}

// ---------------- routing: softmax + top-6 (stable tie-break) ----------------
__global__ __launch_bounds__(256) void k_route(
    const float* __restrict__ logits, int* __restrict__ cnt,
    int* __restrict__ top_ids, float* __restrict__ top_w)
{
    const int lane = threadIdx.x & 63;
    const int t = blockIdx.x * 4 + (threadIdx.x >> 6);

    float v = logits[t * NEXP + lane];
    float m = v;
    #pragma unroll
    for (int s = 32; s > 0; s >>= 1) m = fmaxf(m, __shfl_xor(m, s));
    float ev = expf(v - m);
    float ssum = ev;
    #pragma unroll
    for (int s = 32; s > 0; s >>= 1) ssum += __shfl_xor(ssum, s);
    float p = ev / ssum;

    float pv = p;
    int ids[TOPK]; float wsel[TOPK]; float wsum = 0.f;
    #pragma unroll
    for (int i = 0; i < TOPK; ++i) {
        float mx = pv;
        #pragma unroll
        for (int s = 32; s > 0; s >>= 1) mx = fmaxf(mx, __shfl_xor(mx, s));
        unsigned long long b = __ballot(pv == mx);
        int idx = (int)__builtin_ctzll(b);
        float w = __shfl(p, idx);
        ids[i] = idx; wsel[i] = w; wsum += w;
        if (lane == idx) pv = -1.0f;
    }
    if (lane < TOPK) {
        top_ids[t * TOPK + lane] = ids[lane];
        top_w[t * TOPK + lane]  = wsel[lane] / wsum;
    }
    if (lane == 0) {
        #pragma unroll
        for (int i = 0; i < TOPK; ++i)
            if ((ids[i] & 7) == 0) atomicAdd(&cnt[ids[i] >> 3], 1);
    }
}

__global__ __launch_bounds__(256) void k_scatter(
    const int* __restrict__ top_ids, const float* __restrict__ top_w,
    const int* __restrict__ cnt, int* __restrict__ cnt2,
    int* __restrict__ tok_of, float* __restrict__ w_of)
{
    const int t = blockIdx.x * 256 + threadIdx.x;
    int offs[NLOC];
    {
        int s = 0;
        #pragma unroll
        for (int i = 0; i < NLOC; ++i) { offs[i] = s; s += cnt[i]; }
    }
    #pragma unroll
    for (int i = 0; i < TOPK; ++i) {
        int id = top_ids[t * TOPK + i];
        if ((id & 7) == 0) {
            int e = id >> 3;
            int s = offs[e] + atomicAdd(&cnt2[e], 1);
            tok_of[s] = t;
            w_of[s]  = top_w[t * TOPK + i];
        }
    }
}

// ------------- GEMM1: M=256 x N=32 pair-cols, K-step 64, 2-deep reg prefetch -------------
__global__ __launch_bounds__(256, 2) void k_gemm1(
    const short* __restrict__ xbf, const float* __restrict__ w13,
    const float* __restrict__ w13s, const int* __restrict__ cnt,
    const int* __restrict__ tok_of, short* __restrict__ a_buf)
{
    const int b = blockIdx.x;
    const int e = b & 7;
    const int tt = b >> 3;
    int off_e = 0, cntE = 0;
    #pragma unroll
    for (int i = 0; i < NLOC; ++i) { int c = cnt[i]; if (i < e) off_e += c; if (i == e) cntE = c; }
    const int m0 = (tt / 44) * 256;
    if (m0 >= cntE) return;
    const int n0p = (tt % 44) * 32;           // pair-col base in [0, ITR)
    const int base = off_e + m0;
    const int tid = threadIdx.x;
    const int lane = tid & 63;
    const int wm = tid >> 6;

    __shared__ __align__(16) short As[2][256 * 64];   // 64 KB
    __shared__ __align__(16) short Ws[2][64 * 64];    // 16 KB

    // stage token ids through As[0] (reused before first WRITE)
    int* tokp = (int*)&As[0][0];
    tokp[tid] = tok_of[base + ((m0 + tid < cntE) ? tid : 0)];
    BAR();

    const short* aptr[8];
    int aoff[8];
    #pragma unroll
    for (int p = 0; p < 8; ++p) {
        const int row = p * 32 + (tid >> 3), cg = tid & 7;
        aptr[p] = xbf + (size_t)tokp[row] * HID + cg * 8;
        aoff[p] = (row * 64 + cg * 8) ^ ((row & 7) << 3);
    }
    BAR();   // done reading tokp; As[0] free for staging

    const float* wptr[4];
    int woff[4];
    {
        const float* wg = w13 + ((size_t)e * ITR2 + n0p) * HID;
        const float* wu = w13 + ((size_t)e * ITR2 + ITR + n0p) * HID;
        #pragma unroll
        for (int p = 0; p < 4; ++p) {
            const int row = p * 16 + (tid >> 4), ch = tid & 15;
            wptr[p] = ((p < 2) ? wg : wu) + (size_t)(row & 31) * HID + ch * 4;
            woff[p] = (row * 64 + ch * 4) ^ ((row & 7) << 3);
        }
    }
    const int sgi = (e * 22 + (n0p >> 7)) * 16;
    const int sui = (e * 22 + 11 + (n0p >> 7)) * 16;

    s16x8 ra0[8], ra1[8];
    float4 rw0[4], rw1[4];
    float sg0, su0, sg1, su1;
    f32x4 acc[2][2][4] = {};    // [gate/up][nf][mf]

#define G1_LOAD(kk, S) do {                                                    \
    const int k0 = (kk) * 64;                                                  \
    sg##S = w13s[sgi + ((kk) >> 1)];                                           \
    su##S = w13s[sui + ((kk) >> 1)];                                           \
    _Pragma("unroll")                                                          \
    for (int p = 0; p < 8; ++p) ra##S[p] = *(const s16x8*)(aptr[p] + k0);      \
    _Pragma("unroll")                                                          \
    for (int p = 0; p < 4; ++p) rw##S[p] = *(const float4*)(wptr[p] + k0);     \
} while (0)

#define G1_WRITE(b, S) do {                                                    \
    _Pragma("unroll")                                                          \
    for (int p = 0; p < 8; ++p) *(s16x8*)&As[b][aoff[p]] = ra##S[p];           \
    _Pragma("unroll")                                                          \
    for (int p = 0; p < 4; ++p) {                                              \
        const float s = (p < 2) ? sg##S : su##S;                               \
        s16x4 v = { f2bf(rw##S[p].x * s), f2bf(rw##S[p].y * s),                \
                    f2bf(rw##S[p].z * s), f2bf(rw##S[p].w * s) };              \
        *(s16x4*)&Ws[b][woff[p]] = v;                                          \
    }                                                                          \
} while (0)

#define G1_COMP(b) do {                                                        \
    _Pragma("unroll")                                                          \
    for (int ks = 0; ks < 2; ++ks) {                                           \
        const int co = ks * 32 + (lane >> 4) * 8;                              \
        s16x8 af[4];                                                           \
        _Pragma("unroll")                                                      \
        for (int mf = 0; mf < 4; ++mf) {                                       \
            const int row = wm * 64 + mf * 16 + (lane & 15);                   \
            af[mf] = *(const s16x8*)&As[b][(row * 64 + co) ^ ((row & 7) << 3)];\
        }                                                                      \
        _Pragma("unroll")                                                      \
        for (int t = 0; t < 2; ++t)                                            \
        _Pragma("unroll")                                                      \
        for (int nf = 0; nf < 2; ++nf) {                                       \
            const int row = t * 32 + nf * 16 + (lane & 15);                    \
            s16x8 bv = *(const s16x8*)&Ws[b][(row * 64 + co) ^ ((row & 7) << 3)];\
            _Pragma("unroll")                                                  \
            for (int mf = 0; mf < 4; ++mf)                                     \
                acc[t][nf][mf] = __builtin_amdgcn_mfma_f32_16x16x32_bf16(af[mf], bv, acc[t][nf][mf], 0, 0, 0); \
        }                                                                      \
    }                                                                          \
} while (0)

    G1_LOAD(0, 0);
    G1_WRITE(0, 0);
    G1_LOAD(1, 1);
    BAR();
    for (int k = 0; k < NK1 - 2; k += 2) {
        G1_LOAD(k + 2, 0);      // prefetch k+2, stays in flight across BAR
        G1_COMP(0);
        G1_WRITE(1, 1);         // counted vmcnt: waits k+1's loads only
        BAR();
        G1_LOAD(k + 3, 1);
        G1_COMP(1);
        G1_WRITE(0, 0);
        BAR();
    }
    G1_COMP(0);                 // k = NK1-2
    G1_WRITE(1, 1);
    BAR();
    G1_COMP(1);                 // k = NK1-1

    // epilogue: silu(gate)*up -> a_buf bf16
    #pragma unroll
    for (int nf = 0; nf < 2; ++nf) {
        const int col = n0p + nf * 16 + (lane & 15);
        #pragma unroll
        for (int mf = 0; mf < 4; ++mf)
        #pragma unroll
        for (int j = 0; j < 4; ++j) {
            const int row = wm * 64 + mf * 16 + (lane >> 4) * 4 + j;
            if (m0 + row < cntE) {
                const float g = acc[0][nf][mf][j], u = acc[1][nf][mf][j];
                const float a = (g / (1.f + __expf(-g))) * u;
                a_buf[(size_t)(base + row) * ITR + col] = f2bf(a);
            }
        }
    }
#undef G1_LOAD
#undef G1_WRITE
#undef G1_COMP
}

// ------------- GEMM2: M=256 x N=32 out-cols, K=1408, 2-deep reg prefetch -------------
__global__ __launch_bounds__(256, 2) void k_gemm2(
    const short* __restrict__ a_buf, const float* __restrict__ w2,
    const float* __restrict__ w2s, const int* __restrict__ cnt,
    const int* __restrict__ tok_of, const float* __restrict__ w_of,
    float* __restrict__ out)
{
    const int b = blockIdx.x;
    const int e = b & 7;
    const int tt = b >> 3;
    int off_e = 0, cntE = 0;
    #pragma unroll
    for (int i = 0; i < NLOC; ++i) { int c = cnt[i]; if (i < e) off_e += c; if (i == e) cntE = c; }
    const int m0 = (tt / 64) * 256;
    if (m0 >= cntE) return;
    const int n0 = (tt % 64) * 32;
    const int base = off_e + m0;
    const int tid = threadIdx.x;
    const int lane = tid & 63;
    const int wm = tid >> 6;

    __shared__ __align__(16) short As[2][256 * 64];   // 64 KB
    __shared__ __align__(16) short Ws[2][32 * 64];    // 8 KB

    const short* aptr[8];
    int aoff[8];
    #pragma unroll
    for (int p = 0; p < 8; ++p) {
        const int row = p * 32 + (tid >> 3), cg = tid & 7;
        int srow = base + row; if (srow > NSLOT - 1) srow = NSLOT - 1;
        aptr[p] = a_buf + (size_t)srow * ITR + cg * 8;
        aoff[p] = (row * 64 + cg * 8) ^ ((row & 7) << 3);
    }
    const float* wptr[2];
    int woff[2];
    #pragma unroll
    for (int p = 0; p < 2; ++p) {
        const int row = p * 16 + (tid >> 4), ch = tid & 15;
        wptr[p] = w2 + ((size_t)e * HID + n0 + row) * ITR + ch * 4;
        woff[p] = (row * 64 + ch * 4) ^ ((row & 7) << 3);
    }
    const int sci = (e * 16 + (n0 >> 7)) * 11;

    s16x8 ra0[8], ra1[8];
    float4 rw0[2], rw1[2];
    float sc0, sc1;
    f32x4 acc[2][4] = {};    // [nf][mf]

#define G2_LOAD(kk, S) do {                                                    \
    const int k0 = (kk) * 64;                                                  \
    sc##S = w2s[sci + ((kk) >> 1)];                                            \
    _Pragma("unroll")                                                          \
    for (int p = 0; p < 8; ++p) ra##S[p] = *(const s16x8*)(aptr[p] + k0);      \
    _Pragma("unroll")                                                          \
    for (int p = 0; p < 2; ++p) rw##S[p] = *(const float4*)(wptr[p] + k0);     \
} while (0)

#define G2_WRITE(b, S) do {                                                    \
    _Pragma("unroll")                                                          \
    for (int p = 0; p < 8; ++p) *(s16x8*)&As[b][aoff[p]] = ra##S[p];           \
    _Pragma("unroll")                                                          \
    for (int p = 0; p < 2; ++p) {                                              \
        s16x4 v = { f2bf(rw##S[p].x * sc##S), f2bf(rw##S[p].y * sc##S),        \
                    f2bf(rw##S[p].z * sc##S), f2bf(rw##S[p].w * sc##S) };      \
        *(s16x4*)&Ws[b][woff[p]] = v;                                          \
    }                                                                          \
} while (0)

#define G2_COMP(b) do {                                                        \
    _Pragma("unroll")                                                          \
    for (int ks = 0; ks < 2; ++ks) {                                           \
        const int co = ks * 32 + (lane >> 4) * 8;                              \
        s16x8 af[4];                                                           \
        _Pragma("unroll")                                                      \
        for (int mf = 0; mf < 4; ++mf) {                                       \
            const int row = wm * 64 + mf * 16 + (lane & 15);                   \
            af[mf] = *(const s16x8*)&As[b][(row * 64 + co) ^ ((row & 7) << 3)];\
        }                                                                      \
        _Pragma("unroll")                                                      \
        for (int nf = 0; nf < 2; ++nf) {                                       \
            const int row = nf * 16 + (lane & 15);                             \
            s16x8 bv = *(const s16x8*)&Ws[b][(row * 64 + co) ^ ((row & 7) << 3)];\
            _Pragma("unroll")                                                  \
            for (int mf = 0; mf < 4; ++mf)                                     \
                acc[nf][mf] = __builtin_amdgcn_mfma_f32_16x16x32_bf16(af[mf], bv, acc[nf][mf], 0, 0, 0); \
        }                                                                      \
    }                                                                          \
} while (0)

    G2_LOAD(0, 0);
    G2_WRITE(0, 0);
    G2_LOAD(1, 1);
    BAR();
    for (int k = 0; k < NK2 - 2; k += 2) {
        G2_LOAD(k + 2, 0);
        G2_COMP(0);
        G2_WRITE(1, 1);
        BAR();
        G2_LOAD(k + 3, 1);
        G2_COMP(1);
        G2_WRITE(0, 0);
        BAR();
    }
    G2_COMP(0);
    G2_WRITE(1, 1);
    BAR();
    G2_COMP(1);

    #pragma unroll
    for (int mf = 0; mf < 4; ++mf)
    #pragma unroll
    for (int j = 0; j < 4; ++j) {
        const int row = wm * 64 + mf * 16 + (lane >> 4) * 4 + j;
        if (m0 + row < cntE) {
            const int   t = tok_of[base + row];
            const float w = w_of[base + row];
            #pragma unroll
            for (int nf = 0; nf < 2; ++nf) {
                const int col = n0 + nf * 16 + (lane & 15);
                atomicAdd(&out[(size_t)t * HID + col], acc[nf][mf][j] * w);
            }
        }
    }
#undef G2_LOAD
#undef G2_WRITE
#undef G2_COMP
}

extern "C" void kernel_launch(void* const* d_in, const int* in_sizes, int n_in,
                              void* d_out, int out_size, void* d_ws, size_t ws_size,
                              hipStream_t stream)
{
    const float* x      = (const float*)d_in[0];
    const float* logits = (const float*)d_in[1];
    const float* w13    = (const float*)d_in[2];
    const float* w13s   = (const float*)d_in[3];
    const float* w2     = (const float*)d_in[4];
    const float* w2s    = (const float*)d_in[5];
    float* out = (float*)d_out;
    char*  ws  = (char*)d_ws;

    int*   cnt     = (int*)(ws + OFF_CNT);
    int*   cnt2    = (int*)(ws + OFF_CNT2);
    int*   top_ids = (int*)(ws + OFF_TOPID);
    float* top_w   = (float*)(ws + OFF_TOPW);
    int*   tok_of  = (int*)(ws + OFF_TOK);
    float* w_of    = (float*)(ws + OFF_WOF);
    short* xbf     = (short*)(ws + OFF_XBF);
    short* a_buf   = (short*)(ws + OFF_ABUF);

    k_prep   <<<T_TOK,       256, 0, stream>>>(x, xbf, out, cnt);
    k_route  <<<T_TOK / 4,   256, 0, stream>>>(logits, cnt, top_ids, top_w);
    k_scatter<<<T_TOK / 256, 256, 0, stream>>>(top_ids, top_w, cnt, cnt2, tok_of, w_of);
    k_gemm1  <<<44 * 8 * NLOC, 256, 0, stream>>>(xbf, w13, w13s, cnt, tok_of, a_buf);
    k_gemm2  <<<64 * 8 * NLOC, 256, 0, stream>>>(a_buf, w2, w2s, cnt, tok_of, w_of, out);
}

// Round 7
// 141.572 us; speedup vs baseline: 1.3580x; 1.3580x over previous
//
#include <hip/hip_runtime.h>
#include <hip/hip_bf16.h>
#include <cstdint>

#define T_TOK 2048
#define HID   2048
#define NEXP  64
#define TOPK  6
#define NLOC  8
#define ITR   1408
#define ITR2  2816
#define NSLOT (T_TOK * TOPK)
#define NK1   32   // HID/64
#define NK2   22   // ITR/64

// workspace layout (bytes)
#define OFF_CNT   0
#define OFF_CNT2  32
#define OFF_TOPID 4096
#define OFF_TOPW  (OFF_TOPID + T_TOK * TOPK * 4)
#define OFF_TOK   (OFF_TOPW  + T_TOK * TOPK * 4)
#define OFF_WOF   (OFF_TOK   + NSLOT * 4)
#define OFF_XBF   (OFF_WOF   + NSLOT * 4)
#define OFF_ABUF  (OFF_XBF   + (size_t)T_TOK * HID * 2)

typedef __attribute__((ext_vector_type(4))) float f32x4;
typedef __attribute__((ext_vector_type(8))) short s16x8;
typedef __attribute__((ext_vector_type(4))) short s16x4;

__device__ __forceinline__ short f2bf(float f) {
    union { float f; unsigned u; } v; v.f = f;
    unsigned r = v.u + 0x7FFFu + ((v.u >> 16) & 1u);
    return (short)(r >> 16);
}

// ---------------- prep: zero d_out + counters, cvt x -> bf16 ----------------
__global__ __launch_bounds__(256) void k_prep(const float* __restrict__ x,
                                              short* __restrict__ xbf,
                                              float* __restrict__ out,
                                              int* __restrict__ cnt)
{
    const int r = blockIdx.x;            // 2048 rows
    const int c = threadIdx.x * 8;
    const float4 a = *(const float4*)&x[(size_t)r * HID + c];
    const float4 b = *(const float4*)&x[(size_t)r * HID + c + 4];
    s16x8 v = { f2bf(a.x), f2bf(a.y), f2bf(a.z), f2bf(a.w),
                f2bf(b.x), f2bf(b.y), f2bf(b.z), f2bf(b.w) };
    *(s16x8*)&xbf[(size_t)r * HID + c] = v;
    float4 z = {0.f, 0.f, 0.f, 0.f};
    *(float4*)&out[(size_t)r * HID + c] = z;
    *(float4*)&out[(size_t)r * HID + c + 4] = z;
    if (r == 0 && threadIdx.x < 16) cnt[threadIdx.x] = 0;
}

// ---------------- routing: softmax + top-6 (stable tie-break) ----------------
__global__ __launch_bounds__(256) void k_route(
    const float* __restrict__ logits, int* __restrict__ cnt,
    int* __restrict__ top_ids, float* __restrict__ top_w)
{
    const int lane = threadIdx.x & 63;
    const int t = blockIdx.x * 4 + (threadIdx.x >> 6);

    float v = logits[t * NEXP + lane];
    float m = v;
    #pragma unroll
    for (int s = 32; s > 0; s >>= 1) m = fmaxf(m, __shfl_xor(m, s));
    float ev = expf(v - m);
    float ssum = ev;
    #pragma unroll
    for (int s = 32; s > 0; s >>= 1) ssum += __shfl_xor(ssum, s);
    float p = ev / ssum;

    float pv = p;
    int ids[TOPK]; float wsel[TOPK]; float wsum = 0.f;
    #pragma unroll
    for (int i = 0; i < TOPK; ++i) {
        float mx = pv;
        #pragma unroll
        for (int s = 32; s > 0; s >>= 1) mx = fmaxf(mx, __shfl_xor(mx, s));
        unsigned long long b = __ballot(pv == mx);
        int idx = (int)__builtin_ctzll(b);
        float w = __shfl(p, idx);
        ids[i] = idx; wsel[i] = w; wsum += w;
        if (lane == idx) pv = -1.0f;
    }
    if (lane < TOPK) {
        top_ids[t * TOPK + lane] = ids[lane];
        top_w[t * TOPK + lane]  = wsel[lane] / wsum;
    }
    if (lane == 0) {
        #pragma unroll
        for (int i = 0; i < TOPK; ++i)
            if ((ids[i] & 7) == 0) atomicAdd(&cnt[ids[i] >> 3], 1);
    }
}

__global__ __launch_bounds__(256) void k_scatter(
    const int* __restrict__ top_ids, const float* __restrict__ top_w,
    const int* __restrict__ cnt, int* __restrict__ cnt2,
    int* __restrict__ tok_of, float* __restrict__ w_of)
{
    const int t = blockIdx.x * 256 + threadIdx.x;
    int offs[NLOC];
    {
        int s = 0;
        #pragma unroll
        for (int i = 0; i < NLOC; ++i) { offs[i] = s; s += cnt[i]; }
    }
    #pragma unroll
    for (int i = 0; i < TOPK; ++i) {
        int id = top_ids[t * TOPK + i];
        if ((id & 7) == 0) {
            int e = id >> 3;
            int s = offs[e] + atomicAdd(&cnt2[e], 1);
            tok_of[s] = t;
            w_of[s]  = top_w[t * TOPK + i];
        }
    }
}

// ------------- GEMM1: M=128 x N=32 pair-cols, K-step 64, dbuf LDS (48 KB, 3 blk/CU) -------------
__global__ __launch_bounds__(256, 3) void k_gemm1(
    const short* __restrict__ xbf, const float* __restrict__ w13,
    const float* __restrict__ w13s, const int* __restrict__ cnt,
    const int* __restrict__ tok_of, short* __restrict__ a_buf)
{
    const int b = blockIdx.x;
    const int e = b & 7;
    const int tt = b >> 3;
    int off_e = 0, cntE = 0;
    #pragma unroll
    for (int i = 0; i < NLOC; ++i) { int c = cnt[i]; if (i < e) off_e += c; if (i == e) cntE = c; }
    const int m0 = (tt / 44) * 128;
    if (m0 >= cntE) return;
    const int n0p = (tt % 44) * 32;           // pair-col base in [0, ITR)
    const int base = off_e + m0;
    const int tid = threadIdx.x;
    const int lane = tid & 63;
    const int wm = tid >> 6;                  // wave id 0..3 -> owns rows wm*32..+31

    __shared__ __align__(16) short As[2][128 * 64];   // 32 KB
    __shared__ __align__(16) short Ws[2][64 * 64];    // 16 KB

    // stage token ids through As[0] (reused before first WRITE)
    int* tokp = (int*)&As[0][0];
    if (tid < 128) tokp[tid] = tok_of[base + ((m0 + tid < cntE) ? tid : 0)];
    __syncthreads();

    const short* aptr[4];
    int aoff[4];
    #pragma unroll
    for (int p = 0; p < 4; ++p) {
        const int row = p * 32 + (tid >> 3), cg = tid & 7;
        aptr[p] = xbf + (size_t)tokp[row] * HID + cg * 8;
        aoff[p] = (row * 64 + cg * 8) ^ ((row & 7) << 3);
    }
    __syncthreads();   // done reading tokp; As[0] free for staging

    const float* wptr[4];
    int woff[4];
    {
        const float* wg = w13 + ((size_t)e * ITR2 + n0p) * HID;
        const float* wu = w13 + ((size_t)e * ITR2 + ITR + n0p) * HID;
        #pragma unroll
        for (int p = 0; p < 4; ++p) {
            const int row = p * 16 + (tid >> 4), ch = tid & 15;
            wptr[p] = ((p < 2) ? wg : wu) + (size_t)(row & 31) * HID + ch * 4;
            woff[p] = (row * 64 + ch * 4) ^ ((row & 7) << 3);
        }
    }
    const int sgi = (e * 22 + (n0p >> 7)) * 16;
    const int sui = (e * 22 + 11 + (n0p >> 7)) * 16;

    s16x8 ra[4];
    float4 rw[4];
    float sgv, suv;
    f32x4 acc[2][2][2] = {};    // [gate/up][nf][mf]

#define G1_LOAD(kk) do {                                                       \
    const int k0 = (kk) * 64;                                                  \
    sgv = w13s[sgi + ((kk) >> 1)];                                             \
    suv = w13s[sui + ((kk) >> 1)];                                             \
    _Pragma("unroll")                                                          \
    for (int p = 0; p < 4; ++p) ra[p] = *(const s16x8*)(aptr[p] + k0);         \
    _Pragma("unroll")                                                          \
    for (int p = 0; p < 4; ++p) rw[p] = *(const float4*)(wptr[p] + k0);        \
} while (0)

#define G1_WRITE(b) do {                                                       \
    _Pragma("unroll")                                                          \
    for (int p = 0; p < 4; ++p) *(s16x8*)&As[b][aoff[p]] = ra[p];              \
    _Pragma("unroll")                                                          \
    for (int p = 0; p < 4; ++p) {                                              \
        const float s = (p < 2) ? sgv : suv;                                   \
        s16x4 v = { f2bf(rw[p].x * s), f2bf(rw[p].y * s),                      \
                    f2bf(rw[p].z * s), f2bf(rw[p].w * s) };                    \
        *(s16x4*)&Ws[b][woff[p]] = v;                                          \
    }                                                                          \
} while (0)

#define G1_COMP(b) do {                                                        \
    _Pragma("unroll")                                                          \
    for (int ks = 0; ks < 2; ++ks) {                                           \
        const int co = ks * 32 + (lane >> 4) * 8;                              \
        s16x8 af[2];                                                           \
        _Pragma("unroll")                                                      \
        for (int mf = 0; mf < 2; ++mf) {                                       \
            const int row = wm * 32 + mf * 16 + (lane & 15);                   \
            af[mf] = *(const s16x8*)&As[b][(row * 64 + co) ^ ((row & 7) << 3)];\
        }                                                                      \
        _Pragma("unroll")                                                      \
        for (int t = 0; t < 2; ++t)                                            \
        _Pragma("unroll")                                                      \
        for (int nf = 0; nf < 2; ++nf) {                                       \
            const int row = t * 32 + nf * 16 + (lane & 15);                    \
            s16x8 bv = *(const s16x8*)&Ws[b][(row * 64 + co) ^ ((row & 7) << 3)];\
            _Pragma("unroll")                                                  \
            for (int mf = 0; mf < 2; ++mf)                                     \
                acc[t][nf][mf] = __builtin_amdgcn_mfma_f32_16x16x32_bf16(af[mf], bv, acc[t][nf][mf], 0, 0, 0); \
        }                                                                      \
    }                                                                          \
} while (0)

    G1_LOAD(0);
    G1_WRITE(0);
    __syncthreads();
    #pragma unroll 2
    for (int k = 0; k < NK1; ++k) {
        if (k + 1 < NK1) G1_LOAD(k + 1);
        G1_COMP(k & 1);
        if (k + 1 < NK1) {
            G1_WRITE((k & 1) ^ 1);
            __syncthreads();
        }
    }

    // epilogue: silu(gate)*up -> a_buf bf16
    #pragma unroll
    for (int nf = 0; nf < 2; ++nf) {
        const int col = n0p + nf * 16 + (lane & 15);
        #pragma unroll
        for (int mf = 0; mf < 2; ++mf)
        #pragma unroll
        for (int j = 0; j < 4; ++j) {
            const int row = wm * 32 + mf * 16 + (lane >> 4) * 4 + j;
            if (m0 + row < cntE) {
                const float g = acc[0][nf][mf][j], u = acc[1][nf][mf][j];
                const float a = (g / (1.f + __expf(-g))) * u;
                a_buf[(size_t)(base + row) * ITR + col] = f2bf(a);
            }
        }
    }
#undef G1_LOAD
#undef G1_WRITE
#undef G1_COMP
}

// ------------- GEMM2: M=128 x N=32 out-cols, K=1408, dbuf LDS (40 KB) -------------
__global__ __launch_bounds__(256, 4) void k_gemm2(
    const short* __restrict__ a_buf, const float* __restrict__ w2,
    const float* __restrict__ w2s, const int* __restrict__ cnt,
    const int* __restrict__ tok_of, const float* __restrict__ w_of,
    float* __restrict__ out)
{
    const int b = blockIdx.x;
    const int e = b & 7;
    const int tt = b >> 3;
    int off_e = 0, cntE = 0;
    #pragma unroll
    for (int i = 0; i < NLOC; ++i) { int c = cnt[i]; if (i < e) off_e += c; if (i == e) cntE = c; }
    const int m0 = (tt / 64) * 128;
    if (m0 >= cntE) return;
    const int n0 = (tt % 64) * 32;
    const int base = off_e + m0;
    const int tid = threadIdx.x;
    const int lane = tid & 63;
    const int wm = tid >> 6;

    __shared__ __align__(16) short As[2][128 * 64];   // 32 KB
    __shared__ __align__(16) short Ws[2][32 * 64];    // 8 KB

    const short* aptr[4];
    int aoff[4];
    #pragma unroll
    for (int p = 0; p < 4; ++p) {
        const int row = p * 32 + (tid >> 3), cg = tid & 7;
        int srow = base + row; if (srow > NSLOT - 1) srow = NSLOT - 1;
        aptr[p] = a_buf + (size_t)srow * ITR + cg * 8;
        aoff[p] = (row * 64 + cg * 8) ^ ((row & 7) << 3);
    }
    const float* wptr[2];
    int woff[2];
    #pragma unroll
    for (int p = 0; p < 2; ++p) {
        const int row = p * 16 + (tid >> 4), ch = tid & 15;
        wptr[p] = w2 + ((size_t)e * HID + n0 + row) * ITR + ch * 4;
        woff[p] = (row * 64 + ch * 4) ^ ((row & 7) << 3);
    }
    const int sci = (e * 16 + (n0 >> 7)) * 11;

    s16x8 ra[4];
    float4 rw[2];
    float scv;
    f32x4 acc[2][2] = {};    // [nf][mf]

#define G2_LOAD(kk) do {                                                       \
    const int k0 = (kk) * 64;                                                  \
    scv = w2s[sci + ((kk) >> 1)];                                              \
    _Pragma("unroll")                                                          \
    for (int p = 0; p < 4; ++p) ra[p] = *(const s16x8*)(aptr[p] + k0);         \
    _Pragma("unroll")                                                          \
    for (int p = 0; p < 2; ++p) rw[p] = *(const float4*)(wptr[p] + k0);        \
} while (0)

#define G2_WRITE(b) do {                                                       \
    _Pragma("unroll")                                                          \
    for (int p = 0; p < 4; ++p) *(s16x8*)&As[b][aoff[p]] = ra[p];              \
    _Pragma("unroll")                                                          \
    for (int p = 0; p < 2; ++p) {                                              \
        s16x4 v = { f2bf(rw[p].x * scv), f2bf(rw[p].y * scv),                  \
                    f2bf(rw[p].z * scv), f2bf(rw[p].w * scv) };                \
        *(s16x4*)&Ws[b][woff[p]] = v;                                          \
    }                                                                          \
} while (0)

#define G2_COMP(b) do {                                                        \
    _Pragma("unroll")                                                          \
    for (int ks = 0; ks < 2; ++ks) {                                           \
        const int co = ks * 32 + (lane >> 4) * 8;                              \
        s16x8 af[2];                                                           \
        _Pragma("unroll")                                                      \
        for (int mf = 0; mf < 2; ++mf) {                                       \
            const int row = wm * 32 + mf * 16 + (lane & 15);                   \
            af[mf] = *(const s16x8*)&As[b][(row * 64 + co) ^ ((row & 7) << 3)];\
        }                                                                      \
        _Pragma("unroll")                                                      \
        for (int nf = 0; nf < 2; ++nf) {                                       \
            const int row = nf * 16 + (lane & 15);                             \
            s16x8 bv = *(const s16x8*)&Ws[b][(row * 64 + co) ^ ((row & 7) << 3)];\
            _Pragma("unroll")                                                  \
            for (int mf = 0; mf < 2; ++mf)                                     \
                acc[nf][mf] = __builtin_amdgcn_mfma_f32_16x16x32_bf16(af[mf], bv, acc[nf][mf], 0, 0, 0); \
        }                                                                      \
    }                                                                          \
} while (0)

    G2_LOAD(0);
    G2_WRITE(0);
    __syncthreads();
    #pragma unroll 2
    for (int k = 0; k < NK2; ++k) {
        if (k + 1 < NK2) G2_LOAD(k + 1);
        G2_COMP(k & 1);
        if (k + 1 < NK2) {
            G2_WRITE((k & 1) ^ 1);
            __syncthreads();
        }
    }

    #pragma unroll
    for (int mf = 0; mf < 2; ++mf)
    #pragma unroll
    for (int j = 0; j < 4; ++j) {
        const int row = wm * 32 + mf * 16 + (lane >> 4) * 4 + j;
        if (m0 + row < cntE) {
            const int   t = tok_of[base + row];
            const float w = w_of[base + row];
            #pragma unroll
            for (int nf = 0; nf < 2; ++nf) {
                const int col = n0 + nf * 16 + (lane & 15);
                atomicAdd(&out[(size_t)t * HID + col], acc[nf][mf][j] * w);
            }
        }
    }
#undef G2_LOAD
#undef G2_WRITE
#undef G2_COMP
}

extern "C" void kernel_launch(void* const* d_in, const int* in_sizes, int n_in,
                              void* d_out, int out_size, void* d_ws, size_t ws_size,
                              hipStream_t stream)
{
    const float* x      = (const float*)d_in[0];
    const float* logits = (const float*)d_in[1];
    const float* w13    = (const float*)d_in[2];
    const float* w13s   = (const float*)d_in[3];
    const float* w2     = (const float*)d_in[4];
    const float* w2s    = (const float*)d_in[5];
    float* out = (float*)d_out;
    char*  ws  = (char*)d_ws;

    int*   cnt     = (int*)(ws + OFF_CNT);
    int*   cnt2    = (int*)(ws + OFF_CNT2);
    int*   top_ids = (int*)(ws + OFF_TOPID);
    float* top_w   = (float*)(ws + OFF_TOPW);
    int*   tok_of  = (int*)(ws + OFF_TOK);
    float* w_of    = (float*)(ws + OFF_WOF);
    short* xbf     = (short*)(ws + OFF_XBF);
    short* a_buf   = (short*)(ws + OFF_ABUF);

    k_prep   <<<T_TOK,       256, 0, stream>>>(x, xbf, out, cnt);
    k_route  <<<T_TOK / 4,   256, 0, stream>>>(logits, cnt, top_ids, top_w);
    k_scatter<<<T_TOK / 256, 256, 0, stream>>>(top_ids, top_w, cnt, cnt2, tok_of, w_of);
    // m-major flat ids: live blocks (m0 < cntE) get the lowest dispatch ids
    k_gemm1  <<<44 * 16 * 8, 256, 0, stream>>>(xbf, w13, w13s, cnt, tok_of, a_buf);
    k_gemm2  <<<64 * 16 * 8, 256, 0, stream>>>(a_buf, w2, w2s, cnt, tok_of, w_of, out);
}